// Round 2
// baseline (29395.166 us; speedup 1.0000x reference)
//
#include <hip/hip_runtime.h>
#include <math.h>

#define VSIZE 32000
#define EDIM  200
#define HDIM  512
#define SLEN  64
#define TLEN  64
#define BATCH 64

__device__ __forceinline__ float dot4(const float4 a, const float4 b) {
    return a.x * b.x + a.y * b.y + a.z * b.z + a.w * b.w;
}

__device__ __forceinline__ float sigmoidf_(float x) { return 1.0f / (1.0f + expf(-x)); }

// Zero output slice 0 (t=0 logits are defined as zeros) and the state buffers in ws.
__global__ void init_zero(float* __restrict__ out0, float* __restrict__ wsf) {
    const size_t n_out = (size_t)BATCH * VSIZE;      // 2,048,000
    const size_t n_ws  = 6u * 32768u;                // h0a,h0b,h1a,h1b,c0,c1
    size_t i = (size_t)blockIdx.x * blockDim.x + threadIdx.x;
    size_t stride = (size_t)gridDim.x * blockDim.x;
    for (size_t k = i; k < n_out + n_ws; k += stride) {
        if (k < n_out) out0[k] = 0.0f;
        else           wsf[k - n_out] = 0.0f;
    }
}

// ---------------------------------------------------------------------------
// LSTM layer-0 cell (input = embedding gather of toks). State layout is
// k-blocked-by-4 transposed: elem (k, b) lives at [(k>>2)*256 + b*4 + (k&3)],
// so a thread with lane==b reads float4 {k..k+3} coalesced (lane stride 16B).
// Block: 256 threads = 64 b  x 4 h_local; grid 128 -> h = blk*4 + hl in [0,512).
// ---------------------------------------------------------------------------
__global__ __launch_bounds__(256) void lstm_cell_l0(
    const float* __restrict__ embed, const int* __restrict__ toks,
    const float* __restrict__ Wih, const float* __restrict__ Whh,
    const float* __restrict__ bih, const float* __restrict__ bhh,
    const float* __restrict__ hT_in, float* __restrict__ hT_out,
    float* __restrict__ cT)
{
    __shared__ float xs[(EDIM / 4) * BATCH * 4];  // 50*256 floats = 51.2 KB

    const int tid = threadIdx.x;
    // Stage x_t = embed[toks[b]] into LDS in the blocked-transposed layout.
    {
        const int bb = tid >> 2, q = tid & 3;
        const int tok = toks[bb];
        const float4* src4 = (const float4*)(embed + (size_t)tok * EDIM);
        for (int j = q; j < EDIM / 4; j += 4) {
            float4 v = src4[j];
            float* dst = &xs[j * 256 + bb * 4];
            dst[0] = v.x; dst[1] = v.y; dst[2] = v.z; dst[3] = v.w;
        }
    }
    __syncthreads();

    const int b  = tid & 63;
    const int hl = tid >> 6;
    const int h  = blockIdx.x * 4 + hl;

    float acc0 = 0.f, acc1 = 0.f, acc2 = 0.f, acc3 = 0.f;

    // x @ Wih^T part (K = EDIM)
    {
        const float4* w0 = (const float4*)(Wih + (size_t)(h        ) * EDIM);
        const float4* w1 = (const float4*)(Wih + (size_t)(h +  512 ) * EDIM);
        const float4* w2 = (const float4*)(Wih + (size_t)(h + 1024 ) * EDIM);
        const float4* w3 = (const float4*)(Wih + (size_t)(h + 1536 ) * EDIM);
        for (int j = 0; j < EDIM / 4; ++j) {
            float4 xv = *(const float4*)&xs[j * 256 + b * 4];
            acc0 += dot4(xv, w0[j]);
            acc1 += dot4(xv, w1[j]);
            acc2 += dot4(xv, w2[j]);
            acc3 += dot4(xv, w3[j]);
        }
    }
    // h @ Whh^T part (K = HDIM)
    {
        const float4* u0 = (const float4*)(Whh + (size_t)(h        ) * HDIM);
        const float4* u1 = (const float4*)(Whh + (size_t)(h +  512 ) * HDIM);
        const float4* u2 = (const float4*)(Whh + (size_t)(h + 1024 ) * HDIM);
        const float4* u3 = (const float4*)(Whh + (size_t)(h + 1536 ) * HDIM);
        const float4* hin = (const float4*)hT_in;
        for (int j = 0; j < HDIM / 4; ++j) {
            float4 xv = hin[j * 64 + b];
            acc0 += dot4(xv, u0[j]);
            acc1 += dot4(xv, u1[j]);
            acc2 += dot4(xv, u2[j]);
            acc3 += dot4(xv, u3[j]);
        }
    }

    acc0 += bih[h]        + bhh[h];
    acc1 += bih[h +  512] + bhh[h +  512];
    acc2 += bih[h + 1024] + bhh[h + 1024];
    acc3 += bih[h + 1536] + bhh[h + 1536];

    const int cidx = (h >> 2) * 256 + b * 4 + (h & 3);
    float c_old = cT[cidx];
    float gi = sigmoidf_(acc0);
    float gf = sigmoidf_(acc1);
    float gg = tanhf(acc2);
    float go = sigmoidf_(acc3);
    float c_new = gf * c_old + gi * gg;
    float h_new = go * tanhf(c_new);
    cT[cidx]     = c_new;
    hT_out[cidx] = h_new;
}

// LSTM layer-1 cell: x comes from h0 (already in blocked-transposed layout).
__global__ __launch_bounds__(256) void lstm_cell_l1(
    const float* __restrict__ xT,
    const float* __restrict__ Wih, const float* __restrict__ Whh,
    const float* __restrict__ bih, const float* __restrict__ bhh,
    const float* __restrict__ hT_in, float* __restrict__ hT_out,
    float* __restrict__ cT)
{
    const int tid = threadIdx.x;
    const int b  = tid & 63;
    const int hl = tid >> 6;
    const int h  = blockIdx.x * 4 + hl;

    float acc0 = 0.f, acc1 = 0.f, acc2 = 0.f, acc3 = 0.f;

    {
        const float4* w0 = (const float4*)(Wih + (size_t)(h        ) * HDIM);
        const float4* w1 = (const float4*)(Wih + (size_t)(h +  512 ) * HDIM);
        const float4* w2 = (const float4*)(Wih + (size_t)(h + 1024 ) * HDIM);
        const float4* w3 = (const float4*)(Wih + (size_t)(h + 1536 ) * HDIM);
        const float4* xin = (const float4*)xT;
        for (int j = 0; j < HDIM / 4; ++j) {
            float4 xv = xin[j * 64 + b];
            acc0 += dot4(xv, w0[j]);
            acc1 += dot4(xv, w1[j]);
            acc2 += dot4(xv, w2[j]);
            acc3 += dot4(xv, w3[j]);
        }
    }
    {
        const float4* u0 = (const float4*)(Whh + (size_t)(h        ) * HDIM);
        const float4* u1 = (const float4*)(Whh + (size_t)(h +  512 ) * HDIM);
        const float4* u2 = (const float4*)(Whh + (size_t)(h + 1024 ) * HDIM);
        const float4* u3 = (const float4*)(Whh + (size_t)(h + 1536 ) * HDIM);
        const float4* hin = (const float4*)hT_in;
        for (int j = 0; j < HDIM / 4; ++j) {
            float4 xv = hin[j * 64 + b];
            acc0 += dot4(xv, u0[j]);
            acc1 += dot4(xv, u1[j]);
            acc2 += dot4(xv, u2[j]);
            acc3 += dot4(xv, u3[j]);
        }
    }

    acc0 += bih[h]        + bhh[h];
    acc1 += bih[h +  512] + bhh[h +  512];
    acc2 += bih[h + 1024] + bhh[h + 1024];
    acc3 += bih[h + 1536] + bhh[h + 1536];

    const int cidx = (h >> 2) * 256 + b * 4 + (h & 3);
    float c_old = cT[cidx];
    float gi = sigmoidf_(acc0);
    float gf = sigmoidf_(acc1);
    float gg = tanhf(acc2);
    float go = sigmoidf_(acc3);
    float c_new = gf * c_old + gi * gg;
    float h_new = go * tanhf(c_new);
    cT[cidx]     = c_new;
    hT_out[cidx] = h_new;
}

// logits[b][v] = fc_b[v] + sum_k h1[b][k] * fc_W[v][k]; one thread per (b,v).
// Block: 64 b x 4 v; each fc_W row is read by exactly one block (broadcast
// across the 64 lanes of its wave). Grid = V/4 = 8000 blocks.
__global__ __launch_bounds__(256) void fc_kernel(
    const float* __restrict__ h1T, const float* __restrict__ fcW,
    const float* __restrict__ fcb, float* __restrict__ out_slice)
{
    const int tid = threadIdx.x;
    const int b  = tid & 63;
    const int vl = tid >> 6;
    const int v  = blockIdx.x * 4 + vl;

    const float4* w  = (const float4*)(fcW + (size_t)v * HDIM);
    const float4* hv = (const float4*)h1T;
    float acc = fcb[v];
    for (int j = 0; j < HDIM / 4; ++j) {
        acc += dot4(hv[j * 64 + b], w[j]);
    }
    out_slice[(size_t)b * VSIZE + v] = acc;
}

// Per-b argmax over the logits slice just written, then next-token select.
// First-index tie-break to match jnp.argmax.
__global__ __launch_bounds__(256) void argmax_tok(
    const float* __restrict__ logits, const int* __restrict__ target_row,
    const int* __restrict__ tf_p, int* __restrict__ tok)
{
    const int b = blockIdx.x;
    const float* row = logits + (size_t)b * VSIZE;
    float best = -INFINITY;
    int bidx = 0;
    for (int v = threadIdx.x; v < VSIZE; v += 256) {
        float val = row[v];
        if (val > best) { best = val; bidx = v; }  // ascending v: keeps first max
    }
    __shared__ float sv[256];
    __shared__ int   si[256];
    sv[threadIdx.x] = best; si[threadIdx.x] = bidx;
    __syncthreads();
    for (int s = 128; s > 0; s >>= 1) {
        if (threadIdx.x < s) {
            float ov = sv[threadIdx.x + s]; int oi = si[threadIdx.x + s];
            float mv = sv[threadIdx.x];     int mi = si[threadIdx.x];
            if (ov > mv || (ov == mv && oi < mi)) { sv[threadIdx.x] = ov; si[threadIdx.x] = oi; }
        }
        __syncthreads();
    }
    if (threadIdx.x == 0) {
        tok[b] = (*tf_p > 0) ? target_row[b] : si[0];
    }
}

extern "C" void kernel_launch(void* const* d_in, const int* in_sizes, int n_in,
                              void* d_out, int out_size, void* d_ws, size_t ws_size,
                              hipStream_t stream)
{
    const int*   src      = (const int*)  d_in[0];
    const int*   target   = (const int*)  d_in[1];
    const int*   tf_mask  = (const int*)  d_in[2];
    const float* enc_emb  = (const float*)d_in[3];
    const float* dec_emb  = (const float*)d_in[4];
    const float* eW_ih0 = (const float*)d_in[5],  *eW_hh0 = (const float*)d_in[6];
    const float* eb_ih0 = (const float*)d_in[7],  *eb_hh0 = (const float*)d_in[8];
    const float* eW_ih1 = (const float*)d_in[9],  *eW_hh1 = (const float*)d_in[10];
    const float* eb_ih1 = (const float*)d_in[11], *eb_hh1 = (const float*)d_in[12];
    const float* dW_ih0 = (const float*)d_in[13], *dW_hh0 = (const float*)d_in[14];
    const float* db_ih0 = (const float*)d_in[15], *db_hh0 = (const float*)d_in[16];
    const float* dW_ih1 = (const float*)d_in[17], *dW_hh1 = (const float*)d_in[18];
    const float* db_ih1 = (const float*)d_in[19], *db_hh1 = (const float*)d_in[20];
    const float* fcW    = (const float*)d_in[21];
    const float* fcb    = (const float*)d_in[22];

    float* out = (float*)d_out;
    float* ws  = (float*)d_ws;

    // ws layout (floats): 6 state buffers of 32768 (= 512*64, blocked-transposed)
    float* h0a = ws;
    float* h0b = ws + 32768;
    float* h1a = ws + 2 * 32768;
    float* h1b = ws + 3 * 32768;
    float* c0  = ws + 4 * 32768;
    float* c1  = ws + 5 * 32768;
    int*   tok = (int*)(ws + 6 * 32768);

    init_zero<<<1024, 256, 0, stream>>>(out, ws);

    // ---- Encoder ----
    float* h0in = h0a; float* h0out = h0b;
    float* h1in = h1a; float* h1out = h1b;
    for (int t = 0; t < SLEN; ++t) {
        lstm_cell_l0<<<128, 256, 0, stream>>>(enc_emb, src + t * BATCH,
                                              eW_ih0, eW_hh0, eb_ih0, eb_hh0,
                                              h0in, h0out, c0);
        lstm_cell_l1<<<128, 256, 0, stream>>>(h0out,
                                              eW_ih1, eW_hh1, eb_ih1, eb_hh1,
                                              h1in, h1out, c1);
        float* tmp;
        tmp = h0in; h0in = h0out; h0out = tmp;
        tmp = h1in; h1in = h1out; h1out = tmp;
    }
    // h0in/h1in now hold the encoder-final states; c0/c1 carry over in place.

    // ---- Decoder ----
    const int* toks = target;  // iteration 0 consumes target[0]
    for (int j = 0; j < TLEN - 1; ++j) {
        lstm_cell_l0<<<128, 256, 0, stream>>>(dec_emb, toks,
                                              dW_ih0, dW_hh0, db_ih0, db_hh0,
                                              h0in, h0out, c0);
        lstm_cell_l1<<<128, 256, 0, stream>>>(h0out,
                                              dW_ih1, dW_hh1, db_ih1, db_hh1,
                                              h1in, h1out, c1);
        float* slice = out + (size_t)(j + 1) * BATCH * VSIZE;
        fc_kernel<<<VSIZE / 4, 256, 0, stream>>>(h1out, fcW, fcb, slice);
        if (j < TLEN - 2) {
            argmax_tok<<<BATCH, 256, 0, stream>>>(slice, target + (j + 1) * BATCH,
                                                  tf_mask + (j + 1), tok);
        }
        toks = tok;
        float* tmp;
        tmp = h0in; h0in = h0out; h0out = tmp;
        tmp = h1in; h1in = h1out; h1out = tmp;
    }
}